// Round 2
// baseline (296.945 us; speedup 1.0000x reference)
//
#include <hip/hip_runtime.h>
#include <hip/hip_bf16.h>

#define HID 512
#define NW 64
#define BATCH 524288
#define BLK 4096          // WIDTH*D
#define P3N 12352         // 3*BLK + NW
#define KSPLIT 8

typedef __attribute__((ext_vector_type(8))) short short8;
typedef __attribute__((ext_vector_type(4))) float f32x4;

__device__ __forceinline__ unsigned short f2bf(float f){
  unsigned u = __float_as_uint(f);
  unsigned r = u + 0x7fffu + ((u >> 16) & 1u);
  return (unsigned short)(r >> 16);
}
__device__ __forceinline__ float bf2f(unsigned short s){
  return __uint_as_float(((unsigned)s) << 16);
}
__device__ __forceinline__ float fast_tanh(float x){
  float e = __expf(2.0f * x);               // inf for big x -> rcp=0 -> 1; 0 for small -> -1
  return 1.0f - 2.0f * __builtin_amdgcn_rcpf(e + 1.0f);
}

// ---- hypernet layers 1+2: p2 = tanh(tanh(t*W1+b1) @ W2 + b2) ----
__global__ __launch_bounds__(256) void k_hyper12(
    const float* __restrict__ t, const float* __restrict__ W1, const float* __restrict__ b1,
    const float* __restrict__ W2, const float* __restrict__ b2, float* __restrict__ p2)
{
  __shared__ float sp1[HID];
  int tid = threadIdx.x;
  float tv = t[0];
  for (int i = tid; i < HID; i += 256)
    sp1[i] = tanhf(tv * W1[i] + b1[i]);
  __syncthreads();
  int n = blockIdx.x * 8 + (tid >> 5);
  int sub = tid & 31;
  float acc = 0.f;
  #pragma unroll 4
  for (int j = 0; j < HID/32; ++j){
    int k = sub + 32*j;
    acc += sp1[k] * W2[(size_t)k*HID + n];
  }
  #pragma unroll
  for (int m = 1; m < 32; m <<= 1) acc += __shfl_xor(acc, m);
  if (sub == 0) p2[n] = tanhf(acc + b2[n]);
}

// ---- hypernet layer 3 partials: p3p[s][n] = sum_{k in chunk s} p2[k]*W3[k][n] ----
__global__ __launch_bounds__(256) void k_hyper3(
    const float* __restrict__ p2, const float* __restrict__ W3, float* __restrict__ p3p)
{
  __shared__ float sp2[HID/KSPLIT];
  int tid = threadIdx.x;
  int bn = blockIdx.x % 49;
  int bk = blockIdx.x / 49;
  int k0 = bk * (HID/KSPLIT);
  if (tid < HID/KSPLIT) sp2[tid] = p2[k0 + tid];
  __syncthreads();
  int n = bn*256 + tid;
  if (n < P3N){
    float acc = 0.f;
    const float* w3 = W3 + (size_t)k0 * P3N + n;
    #pragma unroll 8
    for (int k = 0; k < HID/KSPLIT; ++k)
      acc += sp2[k] * w3[(size_t)k * P3N];
    p3p[(size_t)bk * P3N + n] = acc;
  }
}

// ---- derive per-time params: W(bf16 row-major), U^T(bf16), B, wu ----
__global__ __launch_bounds__(256) void k_params(
    const float* __restrict__ p3p, const float* __restrict__ b3,
    unsigned short* __restrict__ Wb, unsigned short* __restrict__ Utb,
    float* __restrict__ Bv, float* __restrict__ wu)
{
  __shared__ float swu[NW];
  int tid = threadIdx.x;
  if (tid < NW) swu[tid] = 0.f;
  __syncthreads();
  for (int i = tid; i < BLK; i += 256){
    float pW = b3[i], pU = b3[BLK + i], pG = b3[2*BLK + i];
    #pragma unroll
    for (int s = 0; s < KSPLIT; ++s){
      pW += p3p[(size_t)s*P3N + i];
      pU += p3p[(size_t)s*P3N + BLK + i];
      pG += p3p[(size_t)s*P3N + 2*BLK + i];
    }
    float sg = 1.0f / (1.0f + expf(-pG));
    float Uv = pU * sg;
    int w = i >> 6, d = i & 63;
    Wb[i] = f2bf(pW);
    Utb[d*NW + w] = f2bf(Uv);
    atomicAdd(&swu[w], pW * Uv);
  }
  __syncthreads();
  if (tid < NW){
    wu[tid] = swu[tid];
    float bb = b3[3*BLK + tid];
    #pragma unroll
    for (int s = 0; s < KSPLIT; ++s) bb += p3p[(size_t)s*P3N + 3*BLK + tid];
    Bv[tid] = bb;
  }
}

// ---- main: per 16-row tile, h=tanh(z@W^T+B) via MFMA, dz=(h@U)/64, trace ----
__global__ __launch_bounds__(256, 2) void k_main(
    const float* __restrict__ z,
    const unsigned short* __restrict__ Wb, const unsigned short* __restrict__ Utb,
    const float* __restrict__ Bv, const float* __restrict__ wu,
    float* __restrict__ dz, float* __restrict__ dlogp)
{
  __shared__ unsigned short hs[4][16][72];   // per-wave h tile, stride 144B (16B aligned rows)
  int tid = threadIdx.x;
  int wv = tid >> 6;
  int lane = tid & 63;
  int r = lane & 15;      // A-row / B-col / acc-col
  int g = lane >> 4;      // k-group

  // B-fragments: W rows (matmul1, gemm-bt pattern) and U^T rows (matmul2)
  short8 Wf[4][2], Uf[4][2];
  #pragma unroll
  for (int n = 0; n < 4; ++n){
    #pragma unroll
    for (int kt = 0; kt < 2; ++kt){
      Wf[n][kt] = *(const short8*)(Wb  + ((n*16 + r)*64 + kt*32 + g*8));
      Uf[n][kt] = *(const short8*)(Utb + ((n*16 + r)*64 + kt*32 + g*8));
    }
  }
  float Bvl[4], wul[4];
  #pragma unroll
  for (int n = 0; n < 4; ++n){ Bvl[n] = Bv[n*16 + r]; wul[n] = wu[n*16 + r]; }

  long rowbase = (long)blockIdx.x * 128 + wv * 32;

  #pragma unroll
  for (int t = 0; t < 2; ++t){
    long tilerow = rowbase + t*16;
    // z A-fragments, split hi/lo bf16 for accuracy
    short8 zh[2], zl[2];
    #pragma unroll
    for (int kt = 0; kt < 2; ++kt){
      const float* zp = z + (tilerow + r)*64 + kt*32 + g*8;
      float4 v0 = *(const float4*)(zp);
      float4 v1 = *(const float4*)(zp + 4);
      float zv[8] = {v0.x, v0.y, v0.z, v0.w, v1.x, v1.y, v1.z, v1.w};
      #pragma unroll
      for (int j = 0; j < 8; ++j){
        unsigned short h_ = f2bf(zv[j]);
        zh[kt][j] = (short)h_;
        zl[kt][j] = (short)f2bf(zv[j] - bf2f(h_));
      }
    }
    // matmul1: acc1[b][w] = z @ W^T
    f32x4 acc1[4];
    #pragma unroll
    for (int n = 0; n < 4; ++n){ f32x4 zro = {0.f,0.f,0.f,0.f}; acc1[n] = zro; }
    #pragma unroll
    for (int kt = 0; kt < 2; ++kt){
      #pragma unroll
      for (int n = 0; n < 4; ++n){
        acc1[n] = __builtin_amdgcn_mfma_f32_16x16x32_bf16(zh[kt], Wf[n][kt], acc1[n], 0,0,0);
        acc1[n] = __builtin_amdgcn_mfma_f32_16x16x32_bf16(zl[kt], Wf[n][kt], acc1[n], 0,0,0);
      }
    }
    // bias + tanh + trace partials + h -> LDS (bf16)
    float tp[4] = {0.f,0.f,0.f,0.f};
    #pragma unroll
    for (int n = 0; n < 4; ++n){
      #pragma unroll
      for (int q = 0; q < 4; ++q){
        float h = fast_tanh(acc1[n][q] + Bvl[n]);
        tp[q] += (1.0f - h*h) * wul[n];
        hs[wv][g*4 + q][n*16 + r] = f2bf(h);
      }
    }
    // trace reduce over the 16-lane group and store dlogp
    #pragma unroll
    for (int q = 0; q < 4; ++q){
      #pragma unroll
      for (int m = 1; m < 16; m <<= 1) tp[q] += __shfl_xor(tp[q], m);
    }
    if (r == 0){
      #pragma unroll
      for (int q = 0; q < 4; ++q)
        dlogp[tilerow + g*4 + q] = -tp[q] * (1.0f/64.0f);
    }
    __syncthreads();
    // h A-fragments from LDS
    short8 hf[2];
    #pragma unroll
    for (int kt = 0; kt < 2; ++kt)
      hf[kt] = *(const short8*)(&hs[wv][r][kt*32 + g*8]);
    // matmul2: acc2[b][d] = h @ U  (U^T rows as B-frags)
    f32x4 acc2[4];
    #pragma unroll
    for (int n = 0; n < 4; ++n){ f32x4 zro = {0.f,0.f,0.f,0.f}; acc2[n] = zro; }
    #pragma unroll
    for (int kt = 0; kt < 2; ++kt){
      #pragma unroll
      for (int n = 0; n < 4; ++n)
        acc2[n] = __builtin_amdgcn_mfma_f32_16x16x32_bf16(hf[kt], Uf[n][kt], acc2[n], 0,0,0);
    }
    // store dz
    #pragma unroll
    for (int n = 0; n < 4; ++n){
      #pragma unroll
      for (int q = 0; q < 4; ++q)
        dz[(tilerow + g*4 + q)*64 + n*16 + r] = acc2[n][q] * (1.0f/64.0f);
    }
    __syncthreads();
  }
}

extern "C" void kernel_launch(void* const* d_in, const int* in_sizes, int n_in,
                              void* d_out, int out_size, void* d_ws, size_t ws_size,
                              hipStream_t stream)
{
  const float* t  = (const float*)d_in[0];
  const float* z  = (const float*)d_in[1];
  // d_in[2] = logp_z (unused by the derivative outputs)
  const float* W1 = (const float*)d_in[3];
  const float* b1 = (const float*)d_in[4];
  const float* W2 = (const float*)d_in[5];
  const float* b2 = (const float*)d_in[6];
  const float* W3 = (const float*)d_in[7];
  const float* b3 = (const float*)d_in[8];

  float* ws   = (float*)d_ws;
  float* p2   = ws;                         // 512 floats
  float* p3p  = ws + 512;                   // 8*12352 floats
  float* tail = ws + 512 + 8*P3N;           // params (16B aligned)
  unsigned short* Wb  = (unsigned short*)(tail);          // 4096 bf16
  unsigned short* Utb = (unsigned short*)(tail + 2048);   // 4096 bf16
  float* Bv = tail + 4096;                  // 64
  float* wu = tail + 4160;                  // 64

  float* dz    = (float*)d_out;
  float* dlogp = dz + (size_t)BATCH*64;

  hipLaunchKernelGGL(k_hyper12, dim3(64),        dim3(256), 0, stream, t, W1, b1, W2, b2, p2);
  hipLaunchKernelGGL(k_hyper3,  dim3(49*KSPLIT), dim3(256), 0, stream, p2, W3, p3p);
  hipLaunchKernelGGL(k_params,  dim3(1),         dim3(256), 0, stream, p3p, b3, Wb, Utb, Bv, wu);
  hipLaunchKernelGGL(k_main,    dim3(BATCH/128), dim3(256), 0, stream, z, Wb, Utb, Bv, wu, dz, dlogp);
}

// Round 3
// 295.080 us; speedup vs baseline: 1.0063x; 1.0063x over previous
//
#include <hip/hip_runtime.h>
#include <hip/hip_bf16.h>

#define HID 512
#define NW 64
#define BATCH 524288
#define BLK 4096          // WIDTH*D
#define P3N 12352         // 3*BLK + NW
#define KSPLIT 8

typedef __attribute__((ext_vector_type(8))) short short8;
typedef __attribute__((ext_vector_type(4))) float f32x4;

union V8 { short8 s; unsigned int w[4]; };

__device__ __forceinline__ unsigned short f2bf(float f){
  unsigned u = __float_as_uint(f);
  unsigned r = u + 0x7fffu + ((u >> 16) & 1u);
  return (unsigned short)(r >> 16);
}
__device__ __forceinline__ float fast_tanh(float x){
  float e = __expf(2.0f * x);               // inf for big x -> rcp=0 -> 1; 0 for small -> -1
  return 1.0f - 2.0f * __builtin_amdgcn_rcpf(e + 1.0f);
}

// hi/lo bf16 split of 8 packed floats: hi = truncate-to-bf16(z), lo = trunc-bf16(z - hi)
__device__ __forceinline__ void split8(f32x4 a, f32x4 b, short8& hi, short8& lo){
  unsigned u0=__float_as_uint(a[0]), u1=__float_as_uint(a[1]),
           u2=__float_as_uint(a[2]), u3=__float_as_uint(a[3]),
           u4=__float_as_uint(b[0]), u5=__float_as_uint(b[1]),
           u6=__float_as_uint(b[2]), u7=__float_as_uint(b[3]);
  V8 H;
  H.w[0] = __builtin_amdgcn_perm(u1, u0, 0x07060302u);
  H.w[1] = __builtin_amdgcn_perm(u3, u2, 0x07060302u);
  H.w[2] = __builtin_amdgcn_perm(u5, u4, 0x07060302u);
  H.w[3] = __builtin_amdgcn_perm(u7, u6, 0x07060302u);
  float l0 = a[0] - __uint_as_float(u0 & 0xffff0000u);
  float l1 = a[1] - __uint_as_float(u1 & 0xffff0000u);
  float l2 = a[2] - __uint_as_float(u2 & 0xffff0000u);
  float l3 = a[3] - __uint_as_float(u3 & 0xffff0000u);
  float l4 = b[0] - __uint_as_float(u4 & 0xffff0000u);
  float l5 = b[1] - __uint_as_float(u5 & 0xffff0000u);
  float l6 = b[2] - __uint_as_float(u6 & 0xffff0000u);
  float l7 = b[3] - __uint_as_float(u7 & 0xffff0000u);
  V8 L;
  L.w[0] = __builtin_amdgcn_perm(__float_as_uint(l1), __float_as_uint(l0), 0x07060302u);
  L.w[1] = __builtin_amdgcn_perm(__float_as_uint(l3), __float_as_uint(l2), 0x07060302u);
  L.w[2] = __builtin_amdgcn_perm(__float_as_uint(l5), __float_as_uint(l4), 0x07060302u);
  L.w[3] = __builtin_amdgcn_perm(__float_as_uint(l7), __float_as_uint(l6), 0x07060302u);
  hi = H.s; lo = L.s;
}

// ---- hypernet layers 1+2: p2 = tanh(tanh(t*W1+b1) @ W2 + b2) ----
__global__ __launch_bounds__(256) void k_hyper12(
    const float* __restrict__ t, const float* __restrict__ W1, const float* __restrict__ b1,
    const float* __restrict__ W2, const float* __restrict__ b2, float* __restrict__ p2)
{
  __shared__ float sp1[HID];
  int tid = threadIdx.x;
  float tv = t[0];
  for (int i = tid; i < HID; i += 256)
    sp1[i] = tanhf(tv * W1[i] + b1[i]);
  __syncthreads();
  int n = blockIdx.x * 8 + (tid >> 5);
  int sub = tid & 31;
  float acc = 0.f;
  #pragma unroll 4
  for (int j = 0; j < HID/32; ++j){
    int k = sub + 32*j;
    acc += sp1[k] * W2[(size_t)k*HID + n];
  }
  #pragma unroll
  for (int m = 1; m < 32; m <<= 1) acc += __shfl_xor(acc, m);
  if (sub == 0) p2[n] = tanhf(acc + b2[n]);
}

// ---- hypernet layer 3 partials: p3p[s][n] = sum_{k in chunk s} p2[k]*W3[k][n] ----
__global__ __launch_bounds__(256) void k_hyper3(
    const float* __restrict__ p2, const float* __restrict__ W3, float* __restrict__ p3p)
{
  __shared__ float sp2[HID/KSPLIT];
  int tid = threadIdx.x;
  int bn = blockIdx.x % 49;
  int bk = blockIdx.x / 49;
  int k0 = bk * (HID/KSPLIT);
  if (tid < HID/KSPLIT) sp2[tid] = p2[k0 + tid];
  __syncthreads();
  int n = bn*256 + tid;
  if (n < P3N){
    float acc = 0.f;
    const float* w3 = W3 + (size_t)k0 * P3N + n;
    #pragma unroll 8
    for (int k = 0; k < HID/KSPLIT; ++k)
      acc += sp2[k] * w3[(size_t)k * P3N];
    p3p[(size_t)bk * P3N + n] = acc;
  }
}

// ---- derive per-time params: W(bf16 row-major), U^T(bf16), B, wu ----
// grid 16 x 256: thread owns i = bid*256+tid; each 64-lane wave covers exactly one w.
__global__ __launch_bounds__(256) void k_params(
    const float* __restrict__ p3p, const float* __restrict__ b3,
    unsigned short* __restrict__ Wb, unsigned short* __restrict__ Utb,
    float* __restrict__ Bv, float* __restrict__ wu)
{
  int tid = threadIdx.x;
  int i = blockIdx.x*256 + tid;
  float pW = b3[i], pU = b3[BLK + i], pG = b3[2*BLK + i];
  #pragma unroll
  for (int s = 0; s < KSPLIT; ++s){
    pW += p3p[(size_t)s*P3N + i];
    pU += p3p[(size_t)s*P3N + BLK + i];
    pG += p3p[(size_t)s*P3N + 2*BLK + i];
  }
  float Uv = pU / (1.0f + expf(-pG));
  int w = i >> 6, d = i & 63;
  Wb[i] = f2bf(pW);
  Utb[d*NW + w] = f2bf(Uv);
  float v = pW * Uv;
  #pragma unroll
  for (int m = 1; m < 64; m <<= 1) v += __shfl_xor(v, m);
  if ((tid & 63) == 0) wu[w] = v;
  if (blockIdx.x == 0 && tid < NW){
    float pB = b3[3*BLK + tid];
    #pragma unroll
    for (int s = 0; s < KSPLIT; ++s) pB += p3p[(size_t)s*P3N + 3*BLK + tid];
    Bv[tid] = pB;
  }
}

// ---- main: h=tanh(z@W^T+B) via MFMA, dz=(U^T@h^T)^T/64 (swapped mm2), trace ----
// No __syncthreads: hs is per-wave (double-buffered by tile parity); intra-wave
// LDS write->read ordering is compiler-enforced (lgkmcnt).
__global__ __launch_bounds__(256, 4) void k_main(
    const float* __restrict__ z,
    const unsigned short* __restrict__ Wb, const unsigned short* __restrict__ Utb,
    const float* __restrict__ Bv, const float* __restrict__ wu,
    float* __restrict__ dz, float* __restrict__ dlogp)
{
  __shared__ unsigned short hs[4][2][16][72];
  const int tid = threadIdx.x;
  const int wv = tid >> 6, lane = tid & 63;
  const int r = lane & 15, g = lane >> 4;

  short8 Wf[4][2], Uf[4][2];
  #pragma unroll
  for (int n = 0; n < 4; ++n){
    #pragma unroll
    for (int kt = 0; kt < 2; ++kt){
      Wf[n][kt] = *(const short8*)(Wb  + ((n*16 + r)*64 + kt*32 + g*8));
      Uf[n][kt] = *(const short8*)(Utb + ((n*16 + r)*64 + kt*32 + g*8));
    }
  }
  float Bvl[4], wul[4];
  #pragma unroll
  for (int n = 0; n < 4; ++n){ Bvl[n] = Bv[n*16 + r]; wul[n] = wu[n*16 + r]; }
  const float swul = wul[0] + wul[1] + wul[2] + wul[3];

  const long rowbase = (long)blockIdx.x * 128 + wv * 32;

  #pragma unroll
  for (int t = 0; t < 2; ++t){
    const long tr_ = rowbase + t*16;
    const float* zp = z + (tr_ + r)*64 + g*8;
    f32x4 za0 = *(const f32x4*)(zp);
    f32x4 za1 = *(const f32x4*)(zp + 4);
    f32x4 zb0 = *(const f32x4*)(zp + 32);
    f32x4 zb1 = *(const f32x4*)(zp + 36);

    short8 zh0, zl0, zh1, zl1;
    split8(za0, za1, zh0, zl0);
    split8(zb0, zb1, zh1, zl1);

    // matmul1: acc1 = z @ W^T  (rows=batch, cols=w)
    f32x4 acc1[4];
    #pragma unroll
    for (int n = 0; n < 4; ++n){ f32x4 zro = {0.f,0.f,0.f,0.f}; acc1[n] = zro; }
    #pragma unroll
    for (int n = 0; n < 4; ++n){
      acc1[n] = __builtin_amdgcn_mfma_f32_16x16x32_bf16(zh0, Wf[n][0], acc1[n], 0,0,0);
      acc1[n] = __builtin_amdgcn_mfma_f32_16x16x32_bf16(zh1, Wf[n][1], acc1[n], 0,0,0);
      acc1[n] = __builtin_amdgcn_mfma_f32_16x16x32_bf16(zl0, Wf[n][0], acc1[n], 0,0,0);
      acc1[n] = __builtin_amdgcn_mfma_f32_16x16x32_bf16(zl1, Wf[n][1], acc1[n], 0,0,0);
    }

    // bias + tanh + trace partials + h -> LDS (bf16)
    float tp[4] = {0.f,0.f,0.f,0.f};
    #pragma unroll
    for (int n = 0; n < 4; ++n){
      #pragma unroll
      for (int q = 0; q < 4; ++q){
        float h = fast_tanh(acc1[n][q] + Bvl[n]);
        tp[q] = fmaf(-h*h, wul[n], tp[q]);
        hs[wv][t][g*4 + q][n*16 + r] =
            (unsigned short)((__float_as_uint(h) + 0x8000u) >> 16);
      }
    }

    // h fragments (B-operand of swapped mm2): lane needs h[b=r][w=kt*32+g*8+j]
    short8 hf0 = *(const short8*)(&hs[wv][t][r][g*8]);
    short8 hf1 = *(const short8*)(&hs[wv][t][r][32 + g*8]);

    // matmul2 swapped: D[d][b] = sum_w U[w][d] h[b][w]
    f32x4 acc2[4];
    #pragma unroll
    for (int n = 0; n < 4; ++n){ f32x4 zro = {0.f,0.f,0.f,0.f}; acc2[n] = zro; }
    #pragma unroll
    for (int n = 0; n < 4; ++n){
      acc2[n] = __builtin_amdgcn_mfma_f32_16x16x32_bf16(Uf[n][0], hf0, acc2[n], 0,0,0);
      acc2[n] = __builtin_amdgcn_mfma_f32_16x16x32_bf16(Uf[n][1], hf1, acc2[n], 0,0,0);
    }
    // store dz: lane holds d = n*16+g*4+{0..3} at batch row b = tr_+r  -> float4
    #pragma unroll
    for (int n = 0; n < 4; ++n){
      f32x4 o = acc2[n] * 0.015625f;
      __builtin_nontemporal_store(o, (f32x4*)(dz + (tr_ + r)*64 + n*16 + g*4));
    }

    // trace reduce across the 16 r-lanes, store dlogp as float4
    #pragma unroll
    for (int q = 0; q < 4; ++q){
      tp[q] += swul;
      tp[q] += __shfl_xor(tp[q], 1);
      tp[q] += __shfl_xor(tp[q], 2);
      tp[q] += __shfl_xor(tp[q], 4);
      tp[q] += __shfl_xor(tp[q], 8);
    }
    if (r == 0){
      f32x4 o = { -tp[0]*0.015625f, -tp[1]*0.015625f,
                  -tp[2]*0.015625f, -tp[3]*0.015625f };
      __builtin_nontemporal_store(o, (f32x4*)(dlogp + tr_ + g*4));
    }
  }
}

extern "C" void kernel_launch(void* const* d_in, const int* in_sizes, int n_in,
                              void* d_out, int out_size, void* d_ws, size_t ws_size,
                              hipStream_t stream)
{
  const float* t  = (const float*)d_in[0];
  const float* z  = (const float*)d_in[1];
  // d_in[2] = logp_z (unused by the derivative outputs)
  const float* W1 = (const float*)d_in[3];
  const float* b1 = (const float*)d_in[4];
  const float* W2 = (const float*)d_in[5];
  const float* b2 = (const float*)d_in[6];
  const float* W3 = (const float*)d_in[7];
  const float* b3 = (const float*)d_in[8];

  float* ws   = (float*)d_ws;
  float* p2   = ws;                         // 512 floats
  float* p3p  = ws + 512;                   // 8*12352 floats
  float* tail = ws + 512 + 8*P3N;           // params (16B aligned)
  unsigned short* Wb  = (unsigned short*)(tail);          // 4096 bf16
  unsigned short* Utb = (unsigned short*)(tail + 2048);   // 4096 bf16
  float* Bv = tail + 4096;                  // 64
  float* wu = tail + 4160;                  // 64

  float* dz    = (float*)d_out;
  float* dlogp = dz + (size_t)BATCH*64;

  hipLaunchKernelGGL(k_hyper12, dim3(64),        dim3(256), 0, stream, t, W1, b1, W2, b2, p2);
  hipLaunchKernelGGL(k_hyper3,  dim3(49*KSPLIT), dim3(256), 0, stream, p2, W3, p3p);
  hipLaunchKernelGGL(k_params,  dim3(16),        dim3(256), 0, stream, p3p, b3, Wb, Utb, Bv, wu);
  hipLaunchKernelGGL(k_main,    dim3(BATCH/128), dim3(256), 0, stream, z, Wb, Utb, Bv, wu, dz, dlogp);
}